// Round 2
// baseline (116.156 us; speedup 1.0000x reference)
//
#include <hip/hip_runtime.h>

// Fused: out = ALPHA*x - ALPHA*x^3 + BETA*(N+S+W+E - 4*x), replication-padded.
// Shape: (16, 1, 1024, 1024) fp32. Ideal HBM traffic ~134 MB -> ~21 us floor.
//
// R1-R2 (prev session): XCD band swizzle, nontemporal stores. ~42 us kernel.
// R3: 8-row register sliding window (each row loaded once/block). Still 42 us,
//     hbm 2.6 TB/s vs 6.3 achievable by the fills in the same run -> the
//     bottleneck is common to both structures, not the decomposition.
// R4 (this round): two structural fixes to the memory stream itself:
//   a) PLAIN stores, not nontemporal. NT bypasses L2 allocation, so reads and
//      writes interleave fine-grained at the HBM controllers and pay bus
//      turnaround constantly. Regular stores batch in L2 and write back in
//      bursts (the m13 copy ubench does 1:1 R/W at 6.29 TB/s this way).
//   b) W/E neighbors via intra-wave shuffles instead of 2 misaligned dword
//      loads per quad (each spanned ~17 cache lines/wave of L1 occupancy).
//      Only lane 0/63 need memory, via exec-masked single-lane loads.

#define ALPHA 400.0f
#define BETA  10000.0f

typedef float vfloat4 __attribute__((ext_vector_type(4)));

__global__ __launch_bounds__(256) void stencil_kernel(const float* __restrict__ x,
                                                      float* __restrict__ out) {
    constexpr int W = 1024;
    constexpr int H = 1024;
    constexpr int R = 8;          // rows per block (divides H; strips never straddle images)
    constexpr int NUM_XCD = 8;

    // XCD swizzle: dispatcher assigns block b -> XCD (b % 8); remap so each XCD
    // owns a contiguous band of strips (2048 % 8 == 0 -> bijective). Adjacent
    // strips (sharing halo rows) are co-resident on the same XCD -> L2 hits.
    const int band  = gridDim.x / NUM_XCD;
    const int strip = (blockIdx.x & (NUM_XCD - 1)) * band + (blockIdx.x >> 3);

    const int row0 = strip * R;
    const int y0   = row0 & (H - 1);          // row within image
    const int x4   = threadIdx.x << 2;        // 0..1020
    const int lane = threadIdx.x & 63;

    const size_t base = (size_t)row0 * W + x4;
    const float* pc = x + base;
    float*       po = out + base;

    const bool ledge = (x4 == 0);             // image left edge (thread 0)
    const bool redge = (x4 == W - 4);         // image right edge (thread 255)

    // Prime the window: n (replication-clamped at image top) and c.
    vfloat4 n = *(const vfloat4*)(pc - ((y0 == 0) ? 0 : W));
    vfloat4 c = *(const vfloat4*)pc;

    #pragma unroll
    for (int r = 0; r < R; ++r) {
        const int y = y0 + r;
        // south row, replication-clamped at image bottom
        const vfloat4 s = *(const vfloat4*)(pc + ((y == H - 1) ? 0 : W));

        // West/East neighbor scalars from adjacent lanes (wave covers 256
        // contiguous columns). Wave-boundary lanes fall back to an
        // exec-masked single-lane load (1 cache line per wave, not 17).
        float wv = __shfl_up(c.w, 1);
        if (lane == 0)  wv = ledge ? c.x : pc[-1];
        float ev = __shfl_down(c.x, 1);
        if (lane == 63) ev = redge ? c.w : pc[4];

        vfloat4 o;
        o.x = ALPHA * c.x - ALPHA * (c.x * c.x * c.x) + BETA * (n.x + s.x + wv  + c.y - 4.0f * c.x);
        o.y = ALPHA * c.y - ALPHA * (c.y * c.y * c.y) + BETA * (n.y + s.y + c.x + c.z - 4.0f * c.y);
        o.z = ALPHA * c.z - ALPHA * (c.z * c.z * c.z) + BETA * (n.z + s.z + c.y + c.w - 4.0f * c.z);
        o.w = ALPHA * c.w - ALPHA * (c.w * c.w * c.w) + BETA * (n.w + s.w + c.z + ev  - 4.0f * c.w);

        *(vfloat4*)po = o;                    // regular store: L2 batches HBM writebacks

        n = c;
        c = s;
        pc += W;
        po += W;
    }
}

extern "C" void kernel_launch(void* const* d_in, const int* in_sizes, int n_in,
                              void* d_out, int out_size, void* d_ws, size_t ws_size,
                              hipStream_t stream) {
    const float* x0 = (const float*)d_in[0];
    float* out = (float*)d_out;
    // out_size = 16*1024*1024 elements -> 16384 rows -> 2048 strips of 8 rows
    constexpr int R = 8;
    const int rows = out_size / 1024;
    const int grid = rows / R;
    stencil_kernel<<<grid, 256, 0, stream>>>(x0, out);
}

// Round 3
// 112.969 us; speedup vs baseline: 1.0282x; 1.0282x over previous
//
#include <hip/hip_runtime.h>

// Fused: out = ALPHA*x - ALPHA*x^3 + BETA*(N+S+W+E - 4*x), replication-padded.
// Shape: (16, 1, 1024, 1024) fp32. Ideal HBM traffic ~134 MB -> ~21 us floor.
// Timed region carries ~85 us of fixed harness poison fills; in-graph stencil
// budget is total-85.
//
// R1-R2 (prev session): XCD band swizzle + NT stores, row-per-block. ~26 us in-graph.
// R3: 8-row register sliding window, NT stores. ~27 us (neutral; VMEM halved
//     but HBM-bound either way).
// R4: plain stores + shfl W/E: +4 us REGRESSION. Plain stores write-allocate
//     64 MB of never-re-read output into the 4 MiB/XCD L2, evicting the input
//     halo window the strips share. Store type matters; NT was right.
// R5 (this round): R4 with NT stores restored — isolates the store effect and
//     keeps the (sound, previously confounded) shfl W/E: W/E neighbors come
//     from adjacent lanes instead of 2 misaligned dword loads per quad;
//     only wave-boundary lanes touch memory (1 cache line/wave, not 17).

#define ALPHA 400.0f
#define BETA  10000.0f

typedef float vfloat4 __attribute__((ext_vector_type(4)));

__global__ __launch_bounds__(256) void stencil_kernel(const float* __restrict__ x,
                                                      float* __restrict__ out) {
    constexpr int W = 1024;
    constexpr int H = 1024;
    constexpr int R = 8;          // rows per block (divides H; strips never straddle images)
    constexpr int NUM_XCD = 8;

    // XCD swizzle: dispatcher assigns block b -> XCD (b % 8); remap so each XCD
    // owns a contiguous band of strips (2048 % 8 == 0 -> bijective). Adjacent
    // strips (sharing halo rows) are co-resident on the same XCD -> L2 hits.
    const int band  = gridDim.x / NUM_XCD;
    const int strip = (blockIdx.x & (NUM_XCD - 1)) * band + (blockIdx.x >> 3);

    const int row0 = strip * R;
    const int y0   = row0 & (H - 1);          // row within image
    const int x4   = threadIdx.x << 2;        // 0..1020
    const int lane = threadIdx.x & 63;

    const size_t base = (size_t)row0 * W + x4;
    const float* pc = x + base;
    float*       po = out + base;

    const bool ledge = (x4 == 0);             // image left edge (thread 0)
    const bool redge = (x4 == W - 4);         // image right edge (thread 255)

    // Prime the window: n (replication-clamped at image top) and c.
    vfloat4 n = *(const vfloat4*)(pc - ((y0 == 0) ? 0 : W));
    vfloat4 c = *(const vfloat4*)pc;

    #pragma unroll
    for (int r = 0; r < R; ++r) {
        const int y = y0 + r;
        // south row, replication-clamped at image bottom
        const vfloat4 s = *(const vfloat4*)(pc + ((y == H - 1) ? 0 : W));

        // West/East neighbor scalars from adjacent lanes (wave covers 256
        // contiguous columns). Wave-boundary lanes fall back to an
        // exec-masked single-lane load (1 cache line per wave).
        float wv = __shfl_up(c.w, 1);
        if (lane == 0)  wv = ledge ? c.x : pc[-1];
        float ev = __shfl_down(c.x, 1);
        if (lane == 63) ev = redge ? c.w : pc[4];

        vfloat4 o;
        o.x = ALPHA * c.x - ALPHA * (c.x * c.x * c.x) + BETA * (n.x + s.x + wv  + c.y - 4.0f * c.x);
        o.y = ALPHA * c.y - ALPHA * (c.y * c.y * c.y) + BETA * (n.y + s.y + c.x + c.z - 4.0f * c.y);
        o.z = ALPHA * c.z - ALPHA * (c.z * c.z * c.z) + BETA * (n.z + s.z + c.y + c.w - 4.0f * c.z);
        o.w = ALPHA * c.w - ALPHA * (c.w * c.w * c.w) + BETA * (n.w + s.w + c.z + ev  - 4.0f * c.w);

        // Output is never re-read: NT store keeps it out of L2 so the input
        // halo window stays resident (R4 showed +4 us when this was plain).
        __builtin_nontemporal_store(o, (vfloat4*)po);

        n = c;
        c = s;
        pc += W;
        po += W;
    }
}

extern "C" void kernel_launch(void* const* d_in, const int* in_sizes, int n_in,
                              void* d_out, int out_size, void* d_ws, size_t ws_size,
                              hipStream_t stream) {
    const float* x0 = (const float*)d_in[0];
    float* out = (float*)d_out;
    // out_size = 16*1024*1024 elements -> 16384 rows -> 2048 strips of 8 rows
    constexpr int R = 8;
    const int rows = out_size / 1024;
    const int grid = rows / R;
    stencil_kernel<<<grid, 256, 0, stream>>>(x0, out);
}

// Round 4
// 110.387 us; speedup vs baseline: 1.0523x; 1.0234x over previous
//
#include <hip/hip_runtime.h>

// Fused: out = ALPHA*x - ALPHA*x^3 + BETA*(N+S+W+E - 4*x), replication-padded.
// Shape: (16, 1, 1024, 1024) fp32. Ideal HBM traffic ~134 MB -> ~21 us floor.
// Timed region carries ~86 us of fixed harness poison fills; in-graph stencil
// budget is total-86.
//
// Ledger: R2 row/block+NT ~111.3 | R3 slide+NT ~112.0 | R4 slide+plain+shfl
// 116.2 (plain stores pollute L2 -> REGRESSION) | R5 slide+NT+shfl 113.0.
// R6 (this round): R3/R5's sliding loop compiled to VGPR_Count=20 -> the
// compiler SERIALIZED the loads (one s-load + vmcnt(0) per iteration, 8
// dependent HBM round-trips per thread; standalone rocprof showed 2.6 TB/s,
// latency-bound, occupancy 58%). Fix: batch-load all R+2=10 rows into a
// register array up-front (10 independent global_load_dwordx4, ONE latency
// exposure), hoist the wave-boundary W/E scalars into a batched exec-masked
// pre-load, then a pure-register compute loop with 8 NT stores.

#define ALPHA 400.0f
#define BETA  10000.0f

typedef float vfloat4 __attribute__((ext_vector_type(4)));

__global__ __launch_bounds__(256) void stencil_kernel(const float* __restrict__ x,
                                                      float* __restrict__ out) {
    constexpr int W = 1024;
    constexpr int H = 1024;
    constexpr int R = 8;          // rows per block (divides H; strips never straddle images)
    constexpr int NUM_XCD = 8;

    // XCD swizzle: dispatcher assigns block b -> XCD (b % 8); remap so each XCD
    // owns a contiguous band of strips (2048 % 8 == 0 -> bijective). Adjacent
    // strips (sharing halo rows) are co-resident on the same XCD -> L2 hits.
    const int band  = gridDim.x / NUM_XCD;
    const int strip = (blockIdx.x & (NUM_XCD - 1)) * band + (blockIdx.x >> 3);

    const int row0 = strip * R;
    const int y0   = row0 & (H - 1);          // row within image (strip-aligned)
    const int x4   = threadIdx.x << 2;        // 0..1020
    const int lane = threadIdx.x & 63;

    const size_t base = (size_t)row0 * W + x4;
    const float* pc = x + base;               // row y0, this thread's 4 columns
    float*       po = out + base;

    const bool ledge = (x4 == 0);             // image left edge (thread 0)
    const bool redge = (x4 == W - 4);         // image right edge (thread 255)

    // ---- Batched load phase: rows y0-1 .. y0+R, all independent ----------
    // rows[0]   = north halo (replication-clamped at image top)
    // rows[i]   = row y0+i-1 for i=1..R
    // rows[R+1] = south halo (replication-clamped at image bottom)
    vfloat4 rows[R + 2];
    rows[0] = *(const vfloat4*)(pc + ((y0 == 0) ? 0 : -W));
    #pragma unroll
    for (int i = 1; i <= R; ++i)
        rows[i] = *(const vfloat4*)(pc + (i - 1) * W);
    rows[R + 1] = *(const vfloat4*)(pc + ((y0 == H - R) ? (R - 1) : R) * W);

    // Wave-boundary W/E scalars (lanes 0 and 63 only), batched too so no
    // memory op remains inside the compute loop. 2 lanes/wave, 1 line each.
    float edge[R];
    const bool need_w = (lane == 0)  && !ledge;
    const bool need_e = (lane == 63) && !redge;
    if (need_w || need_e) {
        const float* ep = pc + (need_w ? -1 : 4);
        #pragma unroll
        for (int r = 0; r < R; ++r) edge[r] = ep[(size_t)r * W];
    }

    // ---- Pure-register compute + store phase ------------------------------
    #pragma unroll
    for (int r = 0; r < R; ++r) {
        const vfloat4 n = rows[r];
        const vfloat4 c = rows[r + 1];
        const vfloat4 s = rows[r + 2];

        // W/E neighbors from adjacent lanes (wave covers 256 contiguous cols)
        float wv = __shfl_up(c.w, 1);
        if (lane == 0)  wv = ledge ? c.x : edge[r];
        float ev = __shfl_down(c.x, 1);
        if (lane == 63) ev = redge ? c.w : edge[r];

        vfloat4 o;
        o.x = ALPHA * c.x - ALPHA * (c.x * c.x * c.x) + BETA * (n.x + s.x + wv  + c.y - 4.0f * c.x);
        o.y = ALPHA * c.y - ALPHA * (c.y * c.y * c.y) + BETA * (n.y + s.y + c.x + c.z - 4.0f * c.y);
        o.z = ALPHA * c.z - ALPHA * (c.z * c.z * c.z) + BETA * (n.z + s.z + c.y + c.w - 4.0f * c.z);
        o.w = ALPHA * c.w - ALPHA * (c.w * c.w * c.w) + BETA * (n.w + s.w + c.z + ev  - 4.0f * c.w);

        // Output never re-read: NT store keeps it out of L2 so the input halo
        // window stays resident (R4 measured +4 us with plain stores).
        __builtin_nontemporal_store(o, (vfloat4*)(po + (size_t)r * W));
    }
}

extern "C" void kernel_launch(void* const* d_in, const int* in_sizes, int n_in,
                              void* d_out, int out_size, void* d_ws, size_t ws_size,
                              hipStream_t stream) {
    const float* x0 = (const float*)d_in[0];
    float* out = (float*)d_out;
    // out_size = 16*1024*1024 elements -> 16384 rows -> 2048 strips of 8 rows
    constexpr int R = 8;
    const int rows = out_size / 1024;
    const int grid = rows / R;
    stencil_kernel<<<grid, 256, 0, stream>>>(x0, out);
}